// Round 2
// baseline (3622.643 us; speedup 1.0000x reference)
//
#include <hip/hip_runtime.h>
#include <stdint.h>

#define N_TOK 8192
#define DMODEL 2048
#define VOCAB 50257
#define VPAD 50432            // 197 * 256
#define IGNORE_INDEX (-100)

#define BM 256
#define BN 256
#define BK 64
#define NKT (DMODEL / BK)     // 32 k-tiles
#define N_RT (N_TOK / BM)     // 32 row tiles
#define N_VT (VPAD / BN)      // 197 vocab tiles

typedef __attribute__((ext_vector_type(8))) short short8;
typedef __attribute__((ext_vector_type(4))) float float4v;

__device__ __forceinline__ unsigned short f32_to_bf16(float f) {
  union { float f; uint32_t u; } v; v.f = f;
  uint32_t u = v.u;
  uint32_t r = u + 0x7fffu + ((u >> 16) & 1u);   // round-to-nearest-even
  return (unsigned short)(r >> 16);
}

__device__ __forceinline__ void gl2lds16(const unsigned short* g, unsigned short* l) {
  __builtin_amdgcn_global_load_lds(
      (const __attribute__((address_space(1))) void*)g,
      (__attribute__((address_space(3))) void*)l,
      16, 0, 0);
}

// ---- conversion kernels -------------------------------------------------

__global__ void convert_c_kernel(const float* __restrict__ c,
                                 unsigned short* __restrict__ cbf) {
  size_t idx4 = (size_t)blockIdx.x * 256 + threadIdx.x;   // 4 elems per thread
  size_t base = idx4 * 4;
  ushort4 o;
  if (base < (size_t)VOCAB * DMODEL) {
    const float4* c4 = (const float4*)c;
    float4 f = c4[idx4];
    o.x = f32_to_bf16(f.x); o.y = f32_to_bf16(f.y);
    o.z = f32_to_bf16(f.z); o.w = f32_to_bf16(f.w);
  } else {
    o.x = 0; o.y = 0; o.z = 0; o.w = 0;                   // pad rows -> 0
  }
  ((ushort4*)cbf)[idx4] = o;
}

__global__ void convert_e_kernel(const float* __restrict__ e,
                                 unsigned short* __restrict__ ebf) {
  size_t idx4 = (size_t)blockIdx.x * 256 + threadIdx.x;
  const float4* e4 = (const float4*)e;
  float4 f = e4[idx4];
  ushort4 o;
  o.x = f32_to_bf16(f.x); o.y = f32_to_bf16(f.y);
  o.z = f32_to_bf16(f.z); o.w = f32_to_bf16(f.w);
  ((ushort4*)ebf)[idx4] = o;
}

__global__ void init_kernel(float* __restrict__ p) {   // zero S and TGT
  int idx = blockIdx.x * 256 + threadIdx.x;
  if (idx < 2 * N_TOK) p[idx] = 0.0f;
}

// ---- fused 256x256 GEMM, 4 phases/K-tile, counted lgkm+vmcnt ------------
//
// LDS map (bytes): buf d in {0,1} at d*65536:
//   +0      A half0 (rows   0..127)   +16384  A half1 (rows 128..255)
//   +32768  B half0 (cols   0..127)   +49152  B half1 (cols 128..255)
// Half layout: 128 rows x 64 bf16, 16B chunk c holds global k-chunk
// c ^ (row&7) (inverse swizzle on global source; LDS dest linear).
//
// Phases per tile t: P0=(A0,B0)->acc00  P1=(A0,B1)->acc01
//                    P2=(A1,B1)->acc11  P3=(A1,B0)->acc10
// Reads are issued ONE PHASE EARLY (overlap MFMA_p with drain of reads_{p+1}):
//   P0 issues rd B1_t      P1 issues rd A1_t
//   P2 issues rd B0_{t+1}  P3 issues rd A0_{t+1}
// Stage slots: P0: B0(t+1)  P1: B1(t+1)  P2: A0(t+2)  P3: A1(t+2)
// Operand reg sets: aX=A0 always, aY=A1 always; bP=B1 (t>=1),
// B0 rotates: t0->bP(prolog), then bR(odd t), bQ(even t).
// vmcnt ledger (2 ops/stage): entering P0_t outstanding={A0,A1(t+1)}=4;
// P2-head vmcnt(2) drains B0(t+1) before its reads; P3-tail vmcnt(4)
// drains B1(t+1) before next tile's reads.

#define BARRIER() do { asm volatile("" ::: "memory"); \
                       __builtin_amdgcn_s_barrier(); \
                       asm volatile("" ::: "memory"); } while (0)
#define LGKM(N)   do { asm volatile("s_waitcnt lgkmcnt(" #N ")" ::: "memory"); \
                       __builtin_amdgcn_sched_barrier(0); } while (0)
#define VMCNT(N)  asm volatile("s_waitcnt vmcnt(" #N ")" ::: "memory")

#define stageA(H, KT2, BUF) do { \
    gl2lds16(gA##H##0 + (size_t)(KT2) * BK, \
             (unsigned short*)((BUF) + (H)*16384 + wid*2048)); \
    gl2lds16(gA##H##1 + (size_t)(KT2) * BK, \
             (unsigned short*)((BUF) + (H)*16384 + wid*2048 + 1024)); \
  } while (0)

#define stageB(H, KT2, BUF) do { \
    gl2lds16(gB##H##0 + (size_t)(KT2) * BK, \
             (unsigned short*)((BUF) + 32768 + (H)*16384 + wid*2048)); \
    gl2lds16(gB##H##1 + (size_t)(KT2) * BK, \
             (unsigned short*)((BUF) + 32768 + (H)*16384 + wid*2048 + 1024)); \
  } while (0)

#define DSA_RD(BUF, SET, QM) do { \
    _Pragma("unroll") \
    for (int i = 0; i < 4; ++i) { \
      SET[i][0] = *(const short8*)((BUF) + (QM)*16384 + aoff + i*2048 + cks0); \
      SET[i][1] = *(const short8*)((BUF) + (QM)*16384 + aoff + i*2048 + cks1); \
    } } while (0)

#define DSB_RD(BUF, SET, QN) do { \
    _Pragma("unroll") \
    for (int j = 0; j < 2; ++j) { \
      SET[j][0] = *(const short8*)((BUF) + 32768 + (QN)*16384 + boff + j*2048 + cks0); \
      SET[j][1] = *(const short8*)((BUF) + 32768 + (QN)*16384 + boff + j*2048 + cks1); \
    } } while (0)

// k outermost: dependent writes to same acc are 8 instructions apart
#define PHASE_MFMA(ASET, BSET, ACC) do { \
    __builtin_amdgcn_s_setprio(1); \
    _Pragma("unroll") \
    for (int k = 0; k < 2; ++k) \
      _Pragma("unroll") \
      for (int i = 0; i < 4; ++i) \
        _Pragma("unroll") \
        for (int j = 0; j < 2; ++j) \
          ACC[i][j] = __builtin_amdgcn_mfma_f32_16x16x32_bf16( \
              ASET[i][k], BSET[j][k], ACC[i][j], 0, 0, 0); \
    __builtin_amdgcn_s_setprio(0); \
  } while (0)

#define KTILE_G(KT, BP0, B1S, BP3, BN0, ST_B, ST_A, RD_N, VM_P2, VM_P3, LG_P2, LG_P3) \
  do { \
    const int _kt = (KT); \
    unsigned char* sd  = sMem + (size_t)((_kt) & 1) * 65536; \
    unsigned char* sdn = sMem + (size_t)(((_kt) & 1) ^ 1) * 65536; \
    /* P0 */ \
    BARRIER(); \
    DSB_RD(sd, B1S, 1); \
    if (ST_B) { stageB(0, _kt + 1, sdn); } \
    LGKM(4); \
    PHASE_MFMA(aX, BP0, acc00); \
    /* P1 */ \
    BARRIER(); \
    DSA_RD(sd, aY, 1); \
    if (ST_B) { stageB(1, _kt + 1, sdn); } \
    LGKM(8); \
    PHASE_MFMA(aX, B1S, acc01); \
    /* P2 */ \
    BARRIER(); \
    VM_P2; \
    if (RD_N) { DSB_RD(sdn, BN0, 0); } \
    if (ST_A) { stageA(0, _kt + 2, sd); } \
    LG_P2; \
    PHASE_MFMA(aY, B1S, acc11); \
    /* P3 */ \
    BARRIER(); \
    if (RD_N) { DSA_RD(sdn, aX, 0); } \
    if (ST_A) { stageA(1, _kt + 2, sd); } \
    LG_P3; \
    PHASE_MFMA(aY, BP3, acc10); \
    VM_P3; \
  } while (0)

#define EPILOG(QM) do { \
    _Pragma("unroll") \
    for (int i = 0; i < 4; ++i) { \
      _Pragma("unroll") \
      for (int t = 0; t < 4; ++t) { \
        const int rloc = (QM)*128 + wm*64 + i*16 + q*4 + t; \
        const int trg  = sTgt[rloc]; \
        float s = 0.0f; \
        _Pragma("unroll") \
        for (int j = 0; j < 2; ++j) { \
          { const int col = col0 + 0*128 + wn*32 + j*16 + m15; \
            const float v = acc##QM##0[i][j][t]; \
            if (col < VOCAB) s += __expf(v); \
            if (col == trg) TGT[row0 + rloc] = v; } \
          { const int col = col0 + 1*128 + wn*32 + j*16 + m15; \
            const float v = acc##QM##1[i][j][t]; \
            if (col < VOCAB) s += __expf(v); \
            if (col == trg) TGT[row0 + rloc] = v; } \
        } \
        _Pragma("unroll") \
        for (int o = 1; o < 16; o <<= 1) s += __shfl_xor(s, o, 64); \
        if (m15 == 0) atomicAdd(&S[row0 + rloc], s); \
      } } } while (0)

__global__ void __launch_bounds__(512, 2) cce_gemm_kernel(
    const unsigned short* __restrict__ ebf,
    const unsigned short* __restrict__ cbf,
    const int* __restrict__ targets,
    float* __restrict__ S,
    float* __restrict__ TGT) {
  __shared__ __align__(16) unsigned char sMem[2 * 65536];   // 128 KB
  __shared__ int sTgt[BM];

  const int bx   = blockIdx.x;
  const int rt   = bx & (N_RT - 1);
  const int vt   = bx >> 5;
  const int row0 = rt * BM;
  const int col0 = vt * BN;

  const int tid  = threadIdx.x;
  const int wid  = tid >> 6;
  const int lane = tid & 63;
  const int wm   = wid >> 2;     // 0..1
  const int wn   = wid & 3;      // 0..3
  const int m15  = lane & 15;
  const int q    = lane >> 4;    // 0..3

  if (tid < BM) sTgt[tid] = targets[row0 + tid];

  // staging: row = wid*16 + (lane>>3) (+8 for second op),
  // global chunk = (lane&7) ^ (lane>>3)   (inverse swizzle, row&7 == lane>>3)
  const int srow = wid * 16 + (lane >> 3);
  const int scol = ((lane & 7) ^ (lane >> 3)) * 8;
  const unsigned short* gA00 = ebf + (size_t)(row0 +   0 + srow + 0) * DMODEL + scol;
  const unsigned short* gA01 = ebf + (size_t)(row0 +   0 + srow + 8) * DMODEL + scol;
  const unsigned short* gA10 = ebf + (size_t)(row0 + 128 + srow + 0) * DMODEL + scol;
  const unsigned short* gA11 = ebf + (size_t)(row0 + 128 + srow + 8) * DMODEL + scol;
  const unsigned short* gB00 = cbf + (size_t)(col0 +   0 + srow + 0) * DMODEL + scol;
  const unsigned short* gB01 = cbf + (size_t)(col0 +   0 + srow + 8) * DMODEL + scol;
  const unsigned short* gB10 = cbf + (size_t)(col0 + 128 + srow + 0) * DMODEL + scol;
  const unsigned short* gB11 = cbf + (size_t)(col0 + 128 + srow + 8) * DMODEL + scol;

  // ds_read offsets: row*128 + (chunk ^ (row&7))*16 ; row&7 == m15&7
  const int aoff = (wm * 64 + m15) * 128;
  const int boff = (wn * 32 + m15) * 128;
  const int cks0 = ((0 + q) ^ (m15 & 7)) * 16;   // kstep 0
  const int cks1 = ((4 + q) ^ (m15 & 7)) * 16;   // kstep 1

  short8 aX[4][2], aY[4][2];              // A0 / A1 operand sets
  short8 bP[2][2], bQ[2][2], bR[2][2];    // rotating B sets
  float4v acc00[4][2], acc01[4][2], acc10[4][2], acc11[4][2];
#pragma unroll
  for (int i = 0; i < 4; ++i)
#pragma unroll
    for (int j = 0; j < 2; ++j) {
      acc00[i][j] = (float4v)0.0f; acc01[i][j] = (float4v)0.0f;
      acc10[i][j] = (float4v)0.0f; acc11[i][j] = (float4v)0.0f;
    }

  // ---- prologue: stage A0(0) A1(0) B0(0) B1(0) -> buf0; A0(1) A1(1) -> buf1
  {
    unsigned char* buf0 = sMem;
    unsigned char* buf1 = sMem + 65536;
    stageA(0, 0, buf0);
    stageA(1, 0, buf0);
    stageB(0, 0, buf0);
    stageB(1, 0, buf0);
    stageA(0, 1, buf1);
    stageA(1, 1, buf1);
    // drain tile-0 data (leave A0(1),A1(1) in flight); drain sTgt ds_write
    asm volatile("s_waitcnt vmcnt(4) lgkmcnt(0)" ::: "memory");
    __builtin_amdgcn_s_barrier();
    asm volatile("" ::: "memory");
    // pre-reads for tile 0 P0: A0_0 -> aX, B0_0 -> bP
    DSA_RD(buf0, aX, 0);
    DSB_RD(buf0, bP, 0);
  }

  // ---- tile 0 (B0_0 in bP from prologue; B1_0 -> bQ) ----
  KTILE_G(0, bP, bQ, bP, bR, 1, 1, 1, VMCNT(2), VMCNT(4), LGKM(4), LGKM(8));

  // ---- steady pairs: odd tile (B0 in bR), even tile (B0 in bQ); B1 -> bP ----
  for (int tp = 0; tp < 15; ++tp) {
    const int to = 2 * tp + 1;
    if (to < NKT - 2) {   // tiles 1..28: full staging
      KTILE_G(to,     bR, bP, bR, bQ, 1, 1, 1, VMCNT(2), VMCNT(4), LGKM(4), LGKM(8));
      KTILE_G(to + 1, bQ, bP, bQ, bR, 1, 1, 1, VMCNT(2), VMCNT(4), LGKM(4), LGKM(8));
    } else {              // tiles 29,30: stop staging A (A(31+) OOB at 29? no: 29 stages A(31) ok, 30 stops)
      KTILE_G(29, bR, bP, bR, bQ, 1, 1, 1, VMCNT(2), VMCNT(4), LGKM(4), LGKM(8));
      KTILE_G(30, bQ, bP, bQ, bR, 1, 0, 1, VMCNT(2), VMCNT(0), LGKM(4), LGKM(8));
    }
  }

  // ---- tile 31 (odd, drain: no stages, no next-tile reads) ----
  KTILE_G(31, bR, bP, bR, bQ, 0, 0, 0, (void)0, (void)0, LGKM(0), LGKM(0));

  // ---- fused epilogue: per-row sum(exp) + target-logit pick ----
  // C/D layout: col = m15, row = q*4 + t
  EPILOG(0);
  EPILOG(1);
}

// ---- finalize -----------------------------------------------------------

__global__ void finalize_kernel(const float* __restrict__ S,
                                const float* __restrict__ TGT,
                                const int* __restrict__ targets,
                                float* __restrict__ out) {
  __shared__ float rs[256];
  __shared__ int   rc[256];
  const int tid = threadIdx.x;
  float acc = 0.0f;
  int cnt = 0;
  for (int r = tid; r < N_TOK; r += 256) {
    const int t = targets[r];
    if (t != IGNORE_INDEX) {
      acc += logf(S[r]) - TGT[r];
      cnt++;
    }
  }
  rs[tid] = acc; rc[tid] = cnt;
  __syncthreads();
  for (int o = 128; o > 0; o >>= 1) {
    if (tid < o) { rs[tid] += rs[tid + o]; rc[tid] += rc[tid + o]; }
    __syncthreads();
  }
  if (tid == 0) out[0] = rs[0] / (float)(rc[0] > 0 ? rc[0] : 1);
}

// ---- launch -------------------------------------------------------------

extern "C" void kernel_launch(void* const* d_in, const int* in_sizes, int n_in,
                              void* d_out, int out_size, void* d_ws, size_t ws_size,
                              hipStream_t stream) {
  const float* e       = (const float*)d_in[0];
  const float* c       = (const float*)d_in[1];
  const int*   targets = (const int*)d_in[2];
  float* out = (float*)d_out;

  char* ws = (char*)d_ws;
  unsigned short* cbf = (unsigned short*)ws;                                   // VPAD*D bf16
  unsigned short* ebf = (unsigned short*)(ws + (size_t)VPAD * DMODEL * 2);     // N_TOK*D bf16
  float* S   = (float*)(ws + (size_t)VPAD * DMODEL * 2 + (size_t)N_TOK * DMODEL * 2);
  float* TGT = S + N_TOK;

  convert_c_kernel<<<dim3((unsigned)((size_t)VPAD * DMODEL / 4 / 256)), dim3(256), 0, stream>>>(c, cbf);
  convert_e_kernel<<<dim3((unsigned)((size_t)N_TOK * DMODEL / 4 / 256)), dim3(256), 0, stream>>>(e, ebf);
  init_kernel<<<dim3((2 * N_TOK + 255) / 256), dim3(256), 0, stream>>>(S);

  cce_gemm_kernel<<<dim3(N_RT * N_VT), dim3(512), 0, stream>>>(ebf, cbf, targets, S, TGT);

  finalize_kernel<<<dim3(1), dim3(256), 0, stream>>>(S, TGT, targets, out);
}

// Round 3
// 2235.268 us; speedup vs baseline: 1.6207x; 1.6207x over previous
//
#include <hip/hip_runtime.h>
#include <stdint.h>

#define N_TOK 8192
#define DMODEL 2048
#define VOCAB 50257
#define VPAD 50432            // 197 * 256
#define IGNORE_INDEX (-100)

#define BM 256
#define BN 256
#define BK 64
#define NKT (DMODEL / BK)     // 32 k-tiles
#define N_RT (N_TOK / BM)     // 32 row tiles
#define N_VT (VPAD / BN)      // 197 vocab tiles

typedef __attribute__((ext_vector_type(8))) short short8;
typedef __attribute__((ext_vector_type(8))) unsigned short ushort8v;
typedef __attribute__((ext_vector_type(4))) float float4v;

__device__ __forceinline__ unsigned short f32_to_bf16(float f) {
  union { float f; uint32_t u; } v; v.f = f;
  uint32_t u = v.u;
  uint32_t r = u + 0x7fffu + ((u >> 16) & 1u);   // round-to-nearest-even
  return (unsigned short)(r >> 16);
}

__device__ __forceinline__ void gl2lds16(const unsigned short* g, unsigned short* l) {
  __builtin_amdgcn_global_load_lds(
      (const __attribute__((address_space(1))) void*)g,
      (__attribute__((address_space(3))) void*)l,
      16, 0, 0);
}

// ---- conversion kernels (8 elems/thread, 16B stores) --------------------

__global__ void convert_c_kernel(const float* __restrict__ c,
                                 unsigned short* __restrict__ cbf) {
  size_t idx8 = (size_t)blockIdx.x * 256 + threadIdx.x;
  size_t base = idx8 * 8;
  ushort8v o;
  if (base < (size_t)VOCAB * DMODEL) {          // VOCAB*DMODEL % 8 == 0
    const float4* c4 = (const float4*)(c + base);
    float4 f0 = c4[0], f1 = c4[1];
    o[0] = f32_to_bf16(f0.x); o[1] = f32_to_bf16(f0.y);
    o[2] = f32_to_bf16(f0.z); o[3] = f32_to_bf16(f0.w);
    o[4] = f32_to_bf16(f1.x); o[5] = f32_to_bf16(f1.y);
    o[6] = f32_to_bf16(f1.z); o[7] = f32_to_bf16(f1.w);
  } else {
    o = (ushort8v)0;                            // pad rows -> 0
  }
  *(ushort8v*)(cbf + base) = o;
}

__global__ void convert_e_kernel(const float* __restrict__ e,
                                 unsigned short* __restrict__ ebf) {
  size_t idx8 = (size_t)blockIdx.x * 256 + threadIdx.x;
  size_t base = idx8 * 8;
  const float4* e4 = (const float4*)(e + base);
  float4 f0 = e4[0], f1 = e4[1];
  ushort8v o;
  o[0] = f32_to_bf16(f0.x); o[1] = f32_to_bf16(f0.y);
  o[2] = f32_to_bf16(f0.z); o[3] = f32_to_bf16(f0.w);
  o[4] = f32_to_bf16(f1.x); o[5] = f32_to_bf16(f1.y);
  o[6] = f32_to_bf16(f1.z); o[7] = f32_to_bf16(f1.w);
  *(ushort8v*)(ebf + base) = o;
}

__global__ void init_kernel(float* __restrict__ p) {   // zero S and TGT
  int idx = blockIdx.x * 256 + threadIdx.x;
  if (idx < 2 * N_TOK) p[idx] = 0.0f;
}

// ---- fused 256x256 GEMM, 4 phases/K-tile, counted lgkm+vmcnt ------------
//
// LDS map (bytes): buf d in {0,1} at d*65536:
//   +0      A half0 (rows   0..127)   +16384  A half1 (rows 128..255)
//   +32768  B half0 (cols   0..127)   +49152  B half1 (cols 128..255)
// Half: 128 rows x 64 bf16 (128B/row); 16B chunk c holds global k-chunk
// c ^ (row&7) (inverse swizzle on global source; LDS dest linear).
//
// Phases (Gray order): P0=(A0,B0)->acc00  P1=(A0,B1)->acc01
//                      P2=(A1,B1)->acc11  P3=(A1,B0)->acc10
// Operand sets (fixed, no rotation): aX=A0, aY=A1, b0=B0, b1=B1.
// Read schedule (one-ahead, drains hide under MFMA):
//   P0: rd b1<-B1(t)[4]          drained by LGKM(8)@P1
//   P1: rd aY<-A1(t)[8]          drained by LGKM(8)@P2
//   P2: VMCNT(6); rd aX<-A0(t+1)[8] from sdn   drained by LGKM(4)@P0(t+1)
//   P3: MFMA; VMCNT(4); rd b0<-B0(t+1)[4] from sdn  drained by LGKM(4)@P0
// Stage slots: P0:B0(t+1)->sdn  P1:B1(t+1)->sdn  P2:A0(t+2)->sd  P3:A1(t+2)->sd
// vmcnt ledger (2 ops/stage, oldest-first): entering P2: {A0,A1(t+1),B0,B1(t+1)}=8
//   -> VMCNT(6) completes A0(t+1). After P2+P3 stages: 10 -> VMCNT(4)
//   completes A1(t+1),B0(t+1),B1(t+1), leaves {A0,A1(t+2)}=4.
// One barrier per phase: every stage target's old readers drained (counted
// lgkm) >=1 barrier before the stage issues  (checked slot-by-slot).

#define BARRIER() do { asm volatile("" ::: "memory"); \
                       __builtin_amdgcn_s_barrier(); \
                       asm volatile("" ::: "memory"); } while (0)
#define LGKM(N)   do { asm volatile("s_waitcnt lgkmcnt(" #N ")" ::: "memory"); \
                       __builtin_amdgcn_sched_barrier(0); } while (0)
#define VMCNT(N)  asm volatile("s_waitcnt vmcnt(" #N ")" ::: "memory")

// staging: SGPR base (readfirstlane) + one shared lane-offset VGPR.
// A half H: +H*128 rows = H*524288 B; second op: +8 rows = 32768 B; k: kt*128 B.
#define stageA(H, KT2, BUF) do { \
    gl2lds16((const unsigned short*)(gA + laneByte + (H)*524288 + (KT2)*128), \
             (unsigned short*)((BUF) + (H)*16384 + wid*2048)); \
    gl2lds16((const unsigned short*)(gA + laneByte + (H)*524288 + 32768 + (KT2)*128), \
             (unsigned short*)((BUF) + (H)*16384 + wid*2048 + 1024)); \
  } while (0)

#define stageB(H, KT2, BUF) do { \
    gl2lds16((const unsigned short*)(gB + laneByte + (H)*524288 + (KT2)*128), \
             (unsigned short*)((BUF) + 32768 + (H)*16384 + wid*2048)); \
    gl2lds16((const unsigned short*)(gB + laneByte + (H)*524288 + 32768 + (KT2)*128), \
             (unsigned short*)((BUF) + 32768 + (H)*16384 + wid*2048 + 1024)); \
  } while (0)

#define DSA_RD(BUF, SET, QM) do { \
    _Pragma("unroll") \
    for (int i = 0; i < 4; ++i) { \
      SET[i][0] = *(const short8*)((BUF) + (QM)*16384 + aoff + i*2048 + cks0); \
      SET[i][1] = *(const short8*)((BUF) + (QM)*16384 + aoff + i*2048 + cks1); \
    } } while (0)

#define DSB_RD(BUF, SET, QN) do { \
    _Pragma("unroll") \
    for (int j = 0; j < 2; ++j) { \
      SET[j][0] = *(const short8*)((BUF) + 32768 + (QN)*16384 + boff + j*2048 + cks0); \
      SET[j][1] = *(const short8*)((BUF) + 32768 + (QN)*16384 + boff + j*2048 + cks1); \
    } } while (0)

// k outermost: dependent writes to same acc are 8 instructions apart
#define PHASE_MFMA(ASET, BSET, ACC) do { \
    __builtin_amdgcn_s_setprio(1); \
    _Pragma("unroll") \
    for (int k = 0; k < 2; ++k) \
      _Pragma("unroll") \
      for (int i = 0; i < 4; ++i) \
        _Pragma("unroll") \
        for (int j = 0; j < 2; ++j) \
          ACC[i][j] = __builtin_amdgcn_mfma_f32_16x16x32_bf16( \
              ASET[i][k], BSET[j][k], ACC[i][j], 0, 0, 0); \
    __builtin_amdgcn_s_setprio(0); \
  } while (0)

#define KTILE(KT, ST_B, ST_A, RD_N, VM_P2, VM_P3, LG_P2) do { \
    const int _kt = (KT); \
    unsigned char* sd  = sMem + (size_t)((_kt) & 1) * 65536; \
    unsigned char* sdn = sMem + (size_t)(((_kt) & 1) ^ 1) * 65536; \
    /* P0 */ \
    BARRIER(); \
    DSB_RD(sd, b1, 1); \
    if (ST_B) { stageB(0, _kt + 1, sdn); } \
    LGKM(4); \
    PHASE_MFMA(aX, b0, acc00); \
    /* P1 */ \
    BARRIER(); \
    DSA_RD(sd, aY, 1); \
    if (ST_B) { stageB(1, _kt + 1, sdn); } \
    LGKM(8); \
    PHASE_MFMA(aX, b1, acc01); \
    /* P2 */ \
    BARRIER(); \
    VM_P2; \
    if (RD_N) { DSA_RD(sdn, aX, 0); } \
    if (ST_A) { stageA(0, _kt + 2, sd); } \
    LG_P2; \
    PHASE_MFMA(aY, b1, acc11); \
    /* P3 */ \
    BARRIER(); \
    if (ST_A) { stageA(1, _kt + 2, sd); } \
    PHASE_MFMA(aY, b0, acc10); \
    VM_P3; \
    if (RD_N) { DSB_RD(sdn, b0, 0); } \
  } while (0)

#define EPILOG(QM) do { \
    _Pragma("unroll") \
    for (int i = 0; i < 4; ++i) { \
      _Pragma("unroll") \
      for (int t = 0; t < 4; ++t) { \
        const int rloc = (QM)*128 + wm*64 + i*16 + q*4 + t; \
        const int trg  = sTgt[rloc]; \
        float s = 0.0f; \
        _Pragma("unroll") \
        for (int j = 0; j < 2; ++j) { \
          { const int col = col0 + 0*128 + wn*32 + j*16 + m15; \
            const float v = acc##QM##0[i][j][t]; \
            if (col < VOCAB) s += __expf(v); \
            if (col == trg) TGT[row0 + rloc] = v; } \
          { const int col = col0 + 1*128 + wn*32 + j*16 + m15; \
            const float v = acc##QM##1[i][j][t]; \
            if (col < VOCAB) s += __expf(v); \
            if (col == trg) TGT[row0 + rloc] = v; } \
        } \
        _Pragma("unroll") \
        for (int o = 1; o < 16; o <<= 1) s += __shfl_xor(s, o, 64); \
        if (m15 == 0) atomicAdd(&S[row0 + rloc], s); \
      } } } while (0)

__global__ void __launch_bounds__(512, 2) cce_gemm_kernel(
    const unsigned short* __restrict__ ebf,
    const unsigned short* __restrict__ cbf,
    const int* __restrict__ targets,
    float* __restrict__ S,
    float* __restrict__ TGT) {
  __shared__ __align__(16) unsigned char sMem[2 * 65536];   // 128 KB
  __shared__ int sTgt[BM];

  const int bx   = blockIdx.x;
  const int rt   = bx & (N_RT - 1);
  const int vt   = bx >> 5;
  const int row0 = rt * BM;
  const int col0 = vt * BN;

  const int tid  = threadIdx.x;
  const int wid  = tid >> 6;
  const int lane = tid & 63;
  const int wm   = wid >> 2;     // 0..1
  const int wn   = wid & 3;      // 0..3
  const int m15  = lane & 15;
  const int q    = lane >> 4;    // 0..3

  if (tid < BM) sTgt[tid] = targets[row0 + tid];

  // staging addressing: uniform byte offsets hoisted to SGPR via
  // readfirstlane (wave-uniform); one per-lane offset VGPR shared by all ops.
  // row = wid*16 + (lane>>3) (+8 for op2); global chunk = (lane&7)^(lane>>3).
  const uint32_t laneByte =
      (uint32_t)((lane >> 3) * (DMODEL * 2) + (((lane & 7) ^ (lane >> 3)) * 16));
  const uint32_t uA = (uint32_t)__builtin_amdgcn_readfirstlane(
      (int)((row0 + wid * 16) * (DMODEL * 2)));
  const uint32_t uB = (uint32_t)__builtin_amdgcn_readfirstlane(
      (int)((col0 + wid * 16) * (DMODEL * 2)));
  const char* gA = (const char*)ebf + uA;
  const char* gB = (const char*)cbf + uB;

  // ds_read offsets: row*128 + (chunk ^ (row&7))*16 ; row&7 == m15&7
  const int aoff = (wm * 64 + m15) * 128;
  const int boff = (wn * 32 + m15) * 128;
  const int cks0 = ((0 + q) ^ (m15 & 7)) * 16;   // kstep 0
  const int cks1 = ((4 + q) ^ (m15 & 7)) * 16;   // kstep 1

  short8 aX[4][2], aY[4][2];      // A0 / A1 operand sets
  short8 b0[2][2], b1[2][2];      // B0 / B1 operand sets
  float4v acc00[4][2], acc01[4][2], acc10[4][2], acc11[4][2];
#pragma unroll
  for (int i = 0; i < 4; ++i)
#pragma unroll
    for (int j = 0; j < 2; ++j) {
      acc00[i][j] = (float4v)0.0f; acc01[i][j] = (float4v)0.0f;
      acc10[i][j] = (float4v)0.0f; acc11[i][j] = (float4v)0.0f;
    }

  // ---- prologue: stage tile0 (all 4 slots)->buf0, tile1 A halves->buf1 ----
  {
    unsigned char* buf0 = sMem;
    unsigned char* buf1 = sMem + 65536;
    stageA(0, 0, buf0);
    stageA(1, 0, buf0);
    stageB(0, 0, buf0);
    stageB(1, 0, buf0);
    stageA(0, 1, buf1);
    stageA(1, 1, buf1);
    // drain tile-0 data (leave A0(1),A1(1) in flight); drain sTgt ds_write
    asm volatile("s_waitcnt vmcnt(4) lgkmcnt(0)" ::: "memory");
    __builtin_amdgcn_s_barrier();
    asm volatile("" ::: "memory");
    // pre-reads for P0(0): aX<-A0(0), b0<-B0(0)  (stay lgkm-outstanding)
    DSA_RD(buf0, aX, 0);
    DSB_RD(buf0, b0, 0);
  }

  // ---- main loop: tiles 0..29 uniform; 30,31 peeled ----
  for (int kt = 0; kt < NKT - 2; ++kt) {
    KTILE(kt, 1, 1, 1, VMCNT(6), VMCNT(4), LGKM(8));
  }
  KTILE(NKT - 2, 1, 0, 1, VMCNT(6), VMCNT(0), LGKM(8));
  KTILE(NKT - 1, 0, 0, 0, (void)0,  (void)0,  LGKM(0));

  // ---- fused epilogue: per-row sum(exp) + target-logit pick ----
  // C/D layout: col = m15, row = q*4 + t
  EPILOG(0);
  EPILOG(1);
}

// ---- finalize -----------------------------------------------------------

__global__ void finalize_kernel(const float* __restrict__ S,
                                const float* __restrict__ TGT,
                                const int* __restrict__ targets,
                                float* __restrict__ out) {
  __shared__ float rs[256];
  __shared__ int   rc[256];
  const int tid = threadIdx.x;
  float acc = 0.0f;
  int cnt = 0;
  for (int r = tid; r < N_TOK; r += 256) {
    const int t = targets[r];
    if (t != IGNORE_INDEX) {
      acc += logf(S[r]) - TGT[r];
      cnt++;
    }
  }
  rs[tid] = acc; rc[tid] = cnt;
  __syncthreads();
  for (int o = 128; o > 0; o >>= 1) {
    if (tid < o) { rs[tid] += rs[tid + o]; rc[tid] += rc[tid + o]; }
    __syncthreads();
  }
  if (tid == 0) out[0] = rs[0] / (float)(rc[0] > 0 ? rc[0] : 1);
}

// ---- launch -------------------------------------------------------------

extern "C" void kernel_launch(void* const* d_in, const int* in_sizes, int n_in,
                              void* d_out, int out_size, void* d_ws, size_t ws_size,
                              hipStream_t stream) {
  const float* e       = (const float*)d_in[0];
  const float* c       = (const float*)d_in[1];
  const int*   targets = (const int*)d_in[2];
  float* out = (float*)d_out;

  char* ws = (char*)d_ws;
  unsigned short* cbf = (unsigned short*)ws;                                   // VPAD*D bf16
  unsigned short* ebf = (unsigned short*)(ws + (size_t)VPAD * DMODEL * 2);     // N_TOK*D bf16
  float* S   = (float*)(ws + (size_t)VPAD * DMODEL * 2 + (size_t)N_TOK * DMODEL * 2);
  float* TGT = S + N_TOK;

  convert_c_kernel<<<dim3((unsigned)((size_t)VPAD * DMODEL / 8 / 256)), dim3(256), 0, stream>>>(c, cbf);
  convert_e_kernel<<<dim3((unsigned)((size_t)N_TOK * DMODEL / 8 / 256)), dim3(256), 0, stream>>>(e, ebf);
  init_kernel<<<dim3((2 * N_TOK + 255) / 256), dim3(256), 0, stream>>>(S);

  cce_gemm_kernel<<<dim3(N_RT * N_VT), dim3(512), 0, stream>>>(ebf, cbf, targets, S, TGT);

  finalize_kernel<<<dim3(1), dim3(256), 0, stream>>>(S, TGT, targets, out);
}